// Round 5
// baseline (76.748 us; speedup 1.0000x reference)
//
#include <hip/hip_runtime.h>
#include <math.h>

// RoI "mod-7" max pooling (JAX reference-exact).
// x: (2, 512, 50, 50) fp32; rois: (R,5) fp32; out: (R, 512, 7, 7) fp32.
//
// Wave layout: lane = half*32 + dx (dx = window column, ftw <= 26), and each
// wave runs FOUR register chains p=0..3 -> 8 channels/wave, 8192 waves.
//
// R4 changes:
//  - NO per-load mask on the fast path: lane dx loads column
//    cx = largest of {dx, dx-7, dx-14, dx-21} below ftw (computed once).
//    Every load is then a valid column of bin dx%7; duplicates are harmless
//    under max, and the 2-shuffle fold over {j, j+7, j+14, j+21} still gives
//    the exact bin max. Inner loop = load + fmax only.
//  - ftw < 7 (clipped rois, empty bin-columns exist) takes a scalar-branch
//    slow path with the old min-clamp + cndmask so empty bins stay -inf
//    (-> 0 after pad clamp, matching segment_max semantics).
//  - 8 channels/wave to halve wave count and amortize decode/epilogue.

#define CH 512
#define IH 50
#define IW 50
#define PLANE (IH * IW)
#define NEG_INF (-__builtin_inff())

template <bool MASK>
__device__ __forceinline__ void run_rows(const float* __restrict__ b0,
                                         int full, int remh, bool colok,
                                         float (&acc)[4][7]) {
  const float* __restrict__ bp[4] = {b0, b0 + PLANE, b0 + 2 * PLANE, b0 + 3 * PLANE};

  // Full super-rows: 28 independent unmasked loads per iteration.
  for (int s = 0; s < full; ++s) {
    const int off = s * 7 * IW;
#pragma unroll
    for (int i = 0; i < 7; ++i) {
#pragma unroll
      for (int p = 0; p < 4; ++p) {
        float v = bp[p][off + i * IW];
        if (MASK) v = colok ? v : NEG_INF;
        acc[p][i] = fmaxf(acc[p][i], v);
      }
    }
  }

  // Tail rows (0..6, wave-uniform count -> scalar skip branches; row fth may
  // lie past the allocation for the last channel, so no row clamping).
  const int toff = full * 7 * IW;
#pragma unroll
  for (int i = 0; i < 7; ++i) {
    if (i < remh) {
#pragma unroll
      for (int p = 0; p < 4; ++p) {
        float v = bp[p][toff + i * IW];
        if (MASK) v = colok ? v : NEG_INF;
        acc[p][i] = fmaxf(acc[p][i], v);
      }
    }
  }
}

__global__ __launch_bounds__(256) void roipool_kernel(
    const float* __restrict__ x, const float* __restrict__ rois,
    float* __restrict__ out) {
  const int r    = blockIdx.y;
  const int wave = threadIdx.x >> 6;   // 0..3
  const int lane = threadIdx.x & 63;
  const int half = lane >> 5;
  const int dx   = lane & 31;          // window column slot (ftw <= 26)

  // roi decode, forced wave-uniform.
  const float* rr = rois + r * 5;
  const int b  = __builtin_amdgcn_readfirstlane((int)rr[0]);
  const int y1 = __builtin_amdgcn_readfirstlane((int)rintf(rr[1] * 0.0625f));
  const int x1 = __builtin_amdgcn_readfirstlane((int)rintf(rr[2] * 0.0625f));
  const int y2 = __builtin_amdgcn_readfirstlane(min((int)rintf(rr[3] * 0.0625f), IH - 1));
  const int x2 = __builtin_amdgcn_readfirstlane(min((int)rintf(rr[4] * 0.0625f), IW - 1));
  const int fth  = y2 - y1 + 1;   // <= 26
  const int ftw  = x2 - x1 + 1;   // <= 26
  const int remh = fth % 7;
  const int remw = ftw % 7;
  const int full = fth / 7;       // 0..3

  // 8 channels per wave: 2 lane-halves x 4 register chains.
  const int cbase = (blockIdx.x * 4 + wave) * 8 + half * 4;  // cbase..cbase+3

  // Same-bin column clamp (fast path): cx = largest {dx-7k} < ftw, k<=4.
  int cx = dx;
  cx = (cx >= ftw) ? cx - 7 : cx;
  cx = (cx >= ftw) ? cx - 7 : cx;
  cx = (cx >= ftw) ? cx - 7 : cx;
  cx = (cx >= ftw) ? cx - 7 : cx;
  const bool ftw_small = ftw < 7;          // scalar (empty bin-columns exist)
  const bool colok = dx < ftw;
  const int  cxs   = min(dx, ftw - 1);     // slow-path clamp

  const float* b0 = x + (size_t)(b * CH + cbase) * PLANE + (y1 * IW + x1)
                      + (ftw_small ? cxs : cx);

  float acc[4][7];
#pragma unroll
  for (int p = 0; p < 4; ++p)
#pragma unroll
    for (int i = 0; i < 7; ++i) acc[p][i] = NEG_INF;

  if (!ftw_small) run_rows<false>(b0, full, remh, true,  acc);
  else            run_rows<true >(b0, full, remh, colok, acc);

  // Column fold: lane j (<7 per half) <- max over {j, j+7, j+14, j+21}.
#pragma unroll
  for (int p = 0; p < 4; ++p) {
#pragma unroll
    for (int i = 0; i < 7; ++i) {
      float a = acc[p][i];
      a = fmaxf(a, __shfl_down(a, 7, 64));
      a = fmaxf(a, __shfl_down(a, 14, 64));
      acc[p][i] = a;
    }
  }

  // Pad-clamp (bins beyond remh/remw -> max(val, 0)) + store.
  if (dx < 7) {
    const int j = dx;
    const bool padc = (remw != 0) && (j >= remw);
    float* o = out + (size_t)(r * CH + cbase) * 49 + j;
#pragma unroll
    for (int p = 0; p < 4; ++p) {
#pragma unroll
      for (int i = 0; i < 7; ++i) {
        float v = acc[p][i];
        const bool padr = (remh != 0) && (i >= remh);
        if (padr | padc) v = fmaxf(v, 0.0f);
        o[p * 49 + i * 7] = v;
      }
    }
  }
}

extern "C" void kernel_launch(void* const* d_in, const int* in_sizes, int n_in,
                              void* d_out, int out_size, void* d_ws, size_t ws_size,
                              hipStream_t stream) {
  const float* x    = (const float*)d_in[0];
  const float* rois = (const float*)d_in[1];
  float* out        = (float*)d_out;
  const int R = in_sizes[1] / 5;  // 128

  dim3 grid(16, R);   // 16 channel-groups (32 ch/block) x R rois = 2048 blocks
  dim3 block(256);    // 4 waves; each wave = 8 channels
  roipool_kernel<<<grid, block, 0, stream>>>(x, rois, out);
}